// Round 1
// baseline (209.038 us; speedup 1.0000x reference)
//
#include <hip/hip_runtime.h>
#include <hip/hip_bf16.h>

#define EPSF 1e-10f

typedef short bf16x8 __attribute__((ext_vector_type(8)));
typedef float f32x4  __attribute__((ext_vector_type(4)));

__device__ __forceinline__ unsigned short f2bf(float f) {
    unsigned int u = __builtin_bit_cast(unsigned int, f);
    u += 0x7fffu + ((u >> 16) & 1u);   // round-to-nearest-even
    return (unsigned short)(u >> 16);
}

// ---------------------------------------------------------------------------
// Pass 1: row sums (d_v) + per-block column partial sums. 256 blocks x 32 rows.
// ---------------------------------------------------------------------------
__global__ __launch_bounds__(256) void deg_kernel(const float* __restrict__ H,
                                                  float* __restrict__ d_v,
                                                  float* __restrict__ colpart) {
    const int t    = threadIdx.x;
    const int b    = blockIdx.x;          // 256 blocks
    const int r0   = b * 32;
    const int lane = t & 63;
    const int wid  = t >> 6;
    __shared__ float wsum[4];

    float ca[32];
#pragma unroll
    for (int i = 0; i < 32; ++i) ca[i] = 0.f;

    for (int r = 0; r < 32; ++r) {
        const float4* row = (const float4*)(H + (size_t)(r0 + r) * 8192);
        float rs = 0.f;
#pragma unroll
        for (int j = 0; j < 8; ++j) {
            float4 v = row[j * 256 + t];
            ca[j * 4 + 0] += v.x; ca[j * 4 + 1] += v.y;
            ca[j * 4 + 2] += v.z; ca[j * 4 + 3] += v.w;
            rs += (v.x + v.y) + (v.z + v.w);
        }
#pragma unroll
        for (int off = 32; off; off >>= 1) rs += __shfl_down(rs, off, 64);
        if (lane == 0) wsum[wid] = rs;
        __syncthreads();
        if (t == 0) d_v[r0 + r] = (wsum[0] + wsum[1]) + (wsum[2] + wsum[3]);
        __syncthreads();
    }

    float* cp = colpart + (size_t)b * 8192;
#pragma unroll
    for (int j = 0; j < 8; ++j) {
        float4 v;
        v.x = ca[j * 4 + 0]; v.y = ca[j * 4 + 1];
        v.z = ca[j * 4 + 2]; v.w = ca[j * 4 + 3];
        ((float4*)cp)[j * 256 + t] = v;
    }
}

// ---------------------------------------------------------------------------
// Pass 2: reduce column partials -> de_inv; also dv_is = rsqrt(d_v+eps).
// ---------------------------------------------------------------------------
__global__ __launch_bounds__(256) void finalize_deg(const float* __restrict__ colpart,
                                                    const float* __restrict__ d_v,
                                                    float* __restrict__ de_inv,
                                                    float* __restrict__ dv_is) {
    const int e = blockIdx.x * 256 + threadIdx.x;   // 8192 threads
    float s = 0.f;
    for (int b = 0; b < 256; ++b) s += colpart[(size_t)b * 8192 + e];
    de_inv[e] = 1.f / (s + EPSF);
    dv_is[e]  = rsqrtf(d_v[e] + EPSF);
}

// ---------------------------------------------------------------------------
// Pass 3: X1t[d][n] = bf16(F[n][d] * dv_is[n])   (transposed, k-contiguous)
// ---------------------------------------------------------------------------
__global__ __launch_bounds__(256) void make_x1t(const float* __restrict__ F,
                                                const float* __restrict__ dv_is,
                                                unsigned short* __restrict__ X1t) {
    const int idx = blockIdx.x * 256 + threadIdx.x;   // 262144 threads
    const int d   = idx & 127;
    const int n0  = (idx >> 7) * 4;
    ushort4 o;
    o.x = f2bf(F[(size_t)(n0 + 0) * 128 + d] * dv_is[n0 + 0]);
    o.y = f2bf(F[(size_t)(n0 + 1) * 128 + d] * dv_is[n0 + 1]);
    o.z = f2bf(F[(size_t)(n0 + 2) * 128 + d] * dv_is[n0 + 2]);
    o.w = f2bf(F[(size_t)(n0 + 3) * 128 + d] * dv_is[n0 + 3]);
    *(ushort4*)&X1t[(size_t)d * 8192 + n0] = o;
}

// ---------------------------------------------------------------------------
// Split-K GEMM.  C[M=8192 rows][128 cols] = A @ B, K = 8192 split 4 ways.
//   TRANS=1 (GEMM1): A[e][k] = H[k][e]   (column access, output rows = edges)
//   TRANS=0 (GEMM2): A[n][k] = H[n][k]   (row access)
//   Bt is [128][8192] bf16, k-contiguous per output column.
//   part[sk][row][col] fp32 partials.
// BM=128, BN=128, BK=64. 256 threads = 4 waves, each wave a 64x64 quadrant
// of 4x4 mfma_f32_16x16x32_bf16 fragments.
// ---------------------------------------------------------------------------
template <int TRANS>
__global__ __launch_bounds__(256) void gemm_sk(const float* __restrict__ H,
                                               const unsigned short* __restrict__ Bt,
                                               float* __restrict__ part) {
    __shared__ alignas(16) unsigned short As[128][72];   // 72 = 64 + 8 pad (144B rows)
    __shared__ alignas(16) unsigned short Bs[128][72];

    const int t    = threadIdx.x;
    const int lane = t & 63;
    const int wid  = t >> 6;
    const int wr   = (wid >> 1) * 64;
    const int wc   = (wid & 1) * 64;
    const int mb   = blockIdx.x;                 // 64
    const int sk   = blockIdx.y;                 // 4
    const size_t mbase = (size_t)mb * 128;
    const int kbase = sk * 2048;

    f32x4 acc[4][4];
#pragma unroll
    for (int m = 0; m < 4; ++m)
#pragma unroll
        for (int n = 0; n < 4; ++n)
#pragma unroll
            for (int i = 0; i < 4; ++i) acc[m][n][i] = 0.f;

    for (int kt = 0; kt < 2048; kt += 64) {
        const int k0 = kbase + kt;

        // ---- stage B tile: Bs[c][kk] = Bt[c][k0+kk], 64B per thread ----
        {
            const int c = t >> 1, half = t & 1;
            const uint4* src = (const uint4*)(Bt + (size_t)c * 8192 + k0 + half * 32);
            uint4* dst = (uint4*)&Bs[c][half * 32];
#pragma unroll
            for (int i = 0; i < 4; ++i) dst[i] = src[i];
        }

        // ---- stage A tile (fp32 -> bf16) ----
        if (TRANS == 0) {
            const int f4i = t & 15;
#pragma unroll
            for (int j = 0; j < 8; ++j) {
                const int m = j * 16 + (t >> 4);
                float4 v = *(const float4*)(H + (mbase + m) * 8192 + k0 + f4i * 4);
                ushort4 o;
                o.x = f2bf(v.x); o.y = f2bf(v.y); o.z = f2bf(v.z); o.w = f2bf(v.w);
                *(ushort4*)&As[m][f4i * 4] = o;
            }
        } else {
            const int c = t & 127, kq = t >> 7;
#pragma unroll
            for (int j = 0; j < 8; ++j) {
                const int kk0 = (j * 2 + kq) * 4;
                float x0 = H[(size_t)(k0 + kk0 + 0) * 8192 + mbase + c];
                float x1 = H[(size_t)(k0 + kk0 + 1) * 8192 + mbase + c];
                float x2 = H[(size_t)(k0 + kk0 + 2) * 8192 + mbase + c];
                float x3 = H[(size_t)(k0 + kk0 + 3) * 8192 + mbase + c];
                ushort4 o;
                o.x = f2bf(x0); o.y = f2bf(x1); o.z = f2bf(x2); o.w = f2bf(x3);
                *(ushort4*)&As[c][kk0] = o;
            }
        }
        __syncthreads();

        // ---- compute: 2 K-substeps of 16 MFMAs ----
#pragma unroll
        for (int ks = 0; ks < 2; ++ks) {
            bf16x8 a[4], b[4];
#pragma unroll
            for (int m = 0; m < 4; ++m)
                a[m] = *(const bf16x8*)&As[wr + m * 16 + (lane & 15)][ks * 32 + (lane >> 4) * 8];
#pragma unroll
            for (int n = 0; n < 4; ++n)
                b[n] = *(const bf16x8*)&Bs[wc + n * 16 + (lane & 15)][ks * 32 + (lane >> 4) * 8];
#pragma unroll
            for (int m = 0; m < 4; ++m)
#pragma unroll
                for (int n = 0; n < 4; ++n)
                    acc[m][n] = __builtin_amdgcn_mfma_f32_16x16x32_bf16(a[m], b[n], acc[m][n], 0, 0, 0);
        }
        __syncthreads();
    }

    // ---- epilogue: write fp32 partials ----
    float* po = part + ((size_t)sk * 8192 + mbase) * 128;
#pragma unroll
    for (int m = 0; m < 4; ++m)
#pragma unroll
        for (int n = 0; n < 4; ++n)
#pragma unroll
            for (int r = 0; r < 4; ++r) {
                const int row = wr + m * 16 + (lane >> 4) * 4 + r;
                const int col = wc + n * 16 + (lane & 15);
                po[(size_t)row * 128 + col] = acc[m][n][r];
            }
}

// ---------------------------------------------------------------------------
// Reduce split-K partials of GEMM1, scale by de_inv, write X2t[d][e] bf16.
// ---------------------------------------------------------------------------
__global__ __launch_bounds__(256) void reduce1(const float* __restrict__ part,
                                               const float* __restrict__ de_inv,
                                               unsigned short* __restrict__ X2t) {
    const int idx = blockIdx.x * 256 + threadIdx.x;   // 262144
    const int d   = idx & 127;
    const int e0  = (idx >> 7) * 4;
    ushort4 o;
#pragma unroll
    for (int i = 0; i < 4; ++i) {
        const size_t base = (size_t)(e0 + i) * 128 + d;
        float s = part[base] + part[base + 1048576] + part[base + 2097152] + part[base + 3145728];
        ((unsigned short*)&o)[i] = f2bf(s * de_inv[e0 + i]);
    }
    *(ushort4*)&X2t[(size_t)d * 8192 + e0] = o;
}

// ---------------------------------------------------------------------------
// Reduce split-K partials of GEMM2, scale by dv_is, write fp32 output.
// ---------------------------------------------------------------------------
__global__ __launch_bounds__(256) void reduce2(const float* __restrict__ part,
                                               const float* __restrict__ dv_is,
                                               float* __restrict__ out) {
    const int idx = blockIdx.x * 256 + threadIdx.x;   // 1048576
    const int n   = idx >> 7;
    float s = part[idx] + part[idx + 1048576] + part[idx + 2097152] + part[idx + 3145728];
    out[idx] = s * dv_is[n];
}

// ---------------------------------------------------------------------------
// Workspace layout (bytes):
//   [0,        16777216)  split-K partials fp32 [4][8192][128]
//                         (aliased: colpart fp32 [256][8192] = 8 MB, dead
//                          before gemm1 writes partials)
//   [16777216, +32768)    d_v
//   [16809984, +32768)    de_inv
//   [16842752, +32768)    dv_is
//   [16875520, +2097152)  X1t bf16 [128][8192]
//   [18972672, +2097152)  X2t bf16 [128][8192]
// total ~20.1 MB
// ---------------------------------------------------------------------------
extern "C" void kernel_launch(void* const* d_in, const int* in_sizes, int n_in,
                              void* d_out, int out_size, void* d_ws, size_t ws_size,
                              hipStream_t stream) {
    const float* H = (const float*)d_in[0];
    const float* F = (const float*)d_in[1];
    float* out = (float*)d_out;
    char* ws = (char*)d_ws;

    float* part            = (float*)(ws);
    float* colpart         = (float*)(ws);
    float* dv              = (float*)(ws + 16777216);
    float* de_inv          = (float*)(ws + 16809984);
    float* dv_is           = (float*)(ws + 16842752);
    unsigned short* X1t    = (unsigned short*)(ws + 16875520);
    unsigned short* X2t    = (unsigned short*)(ws + 18972672);

    deg_kernel  <<<256, 256, 0, stream>>>(H, dv, colpart);
    finalize_deg<<<32, 256, 0, stream>>>(colpart, dv, de_inv, dv_is);
    make_x1t    <<<1024, 256, 0, stream>>>(F, dv_is, X1t);
    gemm_sk<1>  <<<dim3(64, 4), 256, 0, stream>>>(H, X1t, part);
    reduce1     <<<1024, 256, 0, stream>>>(part, de_inv, X2t);
    gemm_sk<0>  <<<dim3(64, 4), 256, 0, stream>>>(H, X2t, part);
    reduce2     <<<4096, 256, 0, stream>>>(part, dv_is, out);
}

// Round 2
// 192.805 us; speedup vs baseline: 1.0842x; 1.0842x over previous
//
#include <hip/hip_runtime.h>
#include <hip/hip_bf16.h>

#define EPSF 1e-10f

typedef short bf16x8 __attribute__((ext_vector_type(8)));
typedef float f32x4  __attribute__((ext_vector_type(4)));

__device__ __forceinline__ unsigned short f2bf(float f) {
    unsigned int u = __builtin_bit_cast(unsigned int, f);
    u += 0x7fffu + ((u >> 16) & 1u);   // round-to-nearest-even
    return (unsigned short)(u >> 16);
}

// ---------------------------------------------------------------------------
// Pass 1: per-row sum -> fold rsqrt(d_v+eps) into bf16 copy of H.
//         Also accumulate per-block column partial sums (for d_e) in fp32.
// 512 blocks x 16 rows.  Hb[n][e] = bf16(dv_is[n] * H[n][e])
// ---------------------------------------------------------------------------
__global__ __launch_bounds__(256) void deg_convert(const float* __restrict__ H,
                                                   unsigned short* __restrict__ Hb,
                                                   float* __restrict__ colpart) {
    const int t    = threadIdx.x;
    const int b    = blockIdx.x;          // 512 blocks
    const int r0   = b * 16;
    const int lane = t & 63;
    const int wid  = t >> 6;
    __shared__ float wsum[4];

    float ca[32];
#pragma unroll
    for (int i = 0; i < 32; ++i) ca[i] = 0.f;

    for (int r = 0; r < 16; ++r) {
        const float4* row = (const float4*)(H + (size_t)(r0 + r) * 8192);
        float4 rv[8];
        float rs = 0.f;
#pragma unroll
        for (int j = 0; j < 8; ++j) {
            rv[j] = row[j * 256 + t];
            ca[j * 4 + 0] += rv[j].x; ca[j * 4 + 1] += rv[j].y;
            ca[j * 4 + 2] += rv[j].z; ca[j * 4 + 3] += rv[j].w;
            rs += (rv[j].x + rv[j].y) + (rv[j].z + rv[j].w);
        }
#pragma unroll
        for (int off = 32; off; off >>= 1) rs += __shfl_down(rs, off, 64);
        if (lane == 0) wsum[wid] = rs;
        __syncthreads();
        const float s = rsqrtf(((wsum[0] + wsum[1]) + (wsum[2] + wsum[3])) + EPSF);
        unsigned short* hrow = Hb + (size_t)(r0 + r) * 8192;
#pragma unroll
        for (int j = 0; j < 8; ++j) {
            ushort4 o;
            o.x = f2bf(rv[j].x * s); o.y = f2bf(rv[j].y * s);
            o.z = f2bf(rv[j].z * s); o.w = f2bf(rv[j].w * s);
            *(ushort4*)&hrow[j * 1024 + t * 4] = o;
        }
        __syncthreads();   // wsum reuse guard
    }

    float* cp = colpart + (size_t)b * 8192;
#pragma unroll
    for (int j = 0; j < 8; ++j) {
        float4 v;
        v.x = ca[j * 4 + 0]; v.y = ca[j * 4 + 1];
        v.z = ca[j * 4 + 2]; v.w = ca[j * 4 + 3];
        ((float4*)cp)[j * 256 + t] = v;
    }
}

// ---------------------------------------------------------------------------
// Pass 2: reduce column partials -> de_inv.
// ---------------------------------------------------------------------------
__global__ __launch_bounds__(256) void finalize_deg(const float* __restrict__ colpart,
                                                    float* __restrict__ de_inv) {
    const int e = blockIdx.x * 256 + threadIdx.x;   // 8192 threads
    float s = 0.f;
    for (int b = 0; b < 512; ++b) s += colpart[(size_t)b * 8192 + e];
    de_inv[e] = 1.f / (s + EPSF);
}

// ---------------------------------------------------------------------------
// Pass 3: Fbt[d][n] = bf16(F[n][d])   (transposed, k-contiguous, NO scale)
// ---------------------------------------------------------------------------
__global__ __launch_bounds__(256) void make_fbt(const float* __restrict__ F,
                                                unsigned short* __restrict__ Fbt) {
    const int idx = blockIdx.x * 256 + threadIdx.x;   // 262144 threads
    const int d   = idx & 127;
    const int n0  = (idx >> 7) * 4;
    ushort4 o;
    o.x = f2bf(F[(size_t)(n0 + 0) * 128 + d]);
    o.y = f2bf(F[(size_t)(n0 + 1) * 128 + d]);
    o.z = f2bf(F[(size_t)(n0 + 2) * 128 + d]);
    o.w = f2bf(F[(size_t)(n0 + 3) * 128 + d]);
    *(ushort4*)&Fbt[(size_t)d * 8192 + n0] = o;
}

// ---------------------------------------------------------------------------
// Split-K GEMM on bf16 Hb.  C[M=8192][128] = A @ B, K = 8192 split 8 ways.
//   TRANS=1 (GEMM1): A[e][k] = Hb[k][e]   (column access)
//   TRANS=0 (GEMM2): A[n][k] = Hb[n][k]   (row access)
//   Bt is [128][8192] bf16 (k-contiguous).  part[sk][row][col] fp32.
// BM=128, BN=128, BK=64; 4 waves, 4x4 frags of 16x16x32 each.
// ---------------------------------------------------------------------------
template <int TRANS>
__global__ __launch_bounds__(256) void gemm_sk(const unsigned short* __restrict__ Hb,
                                               const unsigned short* __restrict__ Bt,
                                               float* __restrict__ part) {
    __shared__ alignas(16) unsigned short As[128][72];   // 144B rows: pad vs conflicts
    __shared__ alignas(16) unsigned short Bs[128][72];

    const int t    = threadIdx.x;
    const int lane = t & 63;
    const int wid  = t >> 6;
    const int wr   = (wid >> 1) * 64;
    const int wc   = (wid & 1) * 64;
    const int mb   = blockIdx.x;                 // 64
    const int sk   = blockIdx.y;                 // 8
    const size_t mbase = (size_t)mb * 128;
    const int kbase = sk * 1024;

    f32x4 acc[4][4];
#pragma unroll
    for (int m = 0; m < 4; ++m)
#pragma unroll
        for (int n = 0; n < 4; ++n)
#pragma unroll
            for (int i = 0; i < 4; ++i) acc[m][n][i] = 0.f;

    for (int kt = 0; kt < 1024; kt += 64) {
        const int k0 = kbase + kt;

        // ---- stage B tile: Bs[c][kk] = Bt[c][k0+kk] ----
        {
            const int c = t >> 1, half = t & 1;
            const uint4* src = (const uint4*)(Bt + (size_t)c * 8192 + k0 + half * 32);
            uint4* dst = (uint4*)&Bs[c][half * 32];
#pragma unroll
            for (int i = 0; i < 4; ++i) dst[i] = src[i];
        }

        // ---- stage A tile ----
        if (TRANS == 0) {
            const int m = t >> 1, half = t & 1;
            const uint4* src = (const uint4*)(Hb + (mbase + m) * 8192 + k0 + half * 32);
            uint4* dst = (uint4*)&As[m][half * 32];
#pragma unroll
            for (int i = 0; i < 4; ++i) dst[i] = src[i];
        } else {
            const int c = t & 127, kq = t >> 7;
            const unsigned short* base = Hb + mbase + c;
#pragma unroll
            for (int j = 0; j < 8; ++j) {
                const int kk0 = (j * 2 + kq) * 4;
                ushort4 o;
                o.x = base[(size_t)(k0 + kk0 + 0) * 8192];
                o.y = base[(size_t)(k0 + kk0 + 1) * 8192];
                o.z = base[(size_t)(k0 + kk0 + 2) * 8192];
                o.w = base[(size_t)(k0 + kk0 + 3) * 8192];
                *(ushort4*)&As[c][kk0] = o;
            }
        }
        __syncthreads();

        // ---- compute: 2 K-substeps of 16 MFMAs ----
#pragma unroll
        for (int ks = 0; ks < 2; ++ks) {
            bf16x8 a[4], b[4];
#pragma unroll
            for (int m = 0; m < 4; ++m)
                a[m] = *(const bf16x8*)&As[wr + m * 16 + (lane & 15)][ks * 32 + (lane >> 4) * 8];
#pragma unroll
            for (int n = 0; n < 4; ++n)
                b[n] = *(const bf16x8*)&Bs[wc + n * 16 + (lane & 15)][ks * 32 + (lane >> 4) * 8];
#pragma unroll
            for (int m = 0; m < 4; ++m)
#pragma unroll
                for (int n = 0; n < 4; ++n)
                    acc[m][n] = __builtin_amdgcn_mfma_f32_16x16x32_bf16(a[m], b[n], acc[m][n], 0, 0, 0);
        }
        __syncthreads();
    }

    float* po = part + ((size_t)sk * 8192 + mbase) * 128;
#pragma unroll
    for (int m = 0; m < 4; ++m)
#pragma unroll
        for (int n = 0; n < 4; ++n)
#pragma unroll
            for (int r = 0; r < 4; ++r) {
                const int row = wr + m * 16 + (lane >> 4) * 4 + r;
                const int col = wc + n * 16 + (lane & 15);
                po[(size_t)row * 128 + col] = acc[m][n][r];
            }
}

// ---------------------------------------------------------------------------
// Reduce 8 split-K partials of GEMM1, scale by de_inv, write X2t[d][e] bf16.
// ---------------------------------------------------------------------------
__global__ __launch_bounds__(256) void reduce1(const float* __restrict__ part,
                                               const float* __restrict__ de_inv,
                                               unsigned short* __restrict__ X2t) {
    const int idx = blockIdx.x * 256 + threadIdx.x;   // 262144
    const int d   = idx & 127;
    const int e0  = (idx >> 7) * 4;
    ushort4 o;
#pragma unroll
    for (int i = 0; i < 4; ++i) {
        const size_t base = (size_t)(e0 + i) * 128 + d;
        float s = 0.f;
#pragma unroll
        for (int sk = 0; sk < 8; ++sk) s += part[base + (size_t)sk * 1048576];
        ((unsigned short*)&o)[i] = f2bf(s * de_inv[e0 + i]);
    }
    *(ushort4*)&X2t[(size_t)d * 8192 + e0] = o;
}

// ---------------------------------------------------------------------------
// Reduce 8 split-K partials of GEMM2 -> fp32 output (dv_is already folded).
// ---------------------------------------------------------------------------
__global__ __launch_bounds__(256) void reduce2(const float* __restrict__ part,
                                               float* __restrict__ out) {
    const int idx = blockIdx.x * 256 + threadIdx.x;   // 1048576
    float s = 0.f;
#pragma unroll
    for (int sk = 0; sk < 8; ++sk) s += part[idx + (size_t)sk * 1048576];
    out[idx] = s;
}

// ---------------------------------------------------------------------------
// Workspace layout (bytes):
//   [0,        33554432)   split-K partials fp32 [8][8192][128]  (32 MB)
//                          (first 16 MB aliased as colpart [512][8192], dead
//                           after finalize_deg)
//   [33554432, +32768)     de_inv
//   [33587200, +2097152)   Fbt bf16 [128][8192]
//   [35684352, +2097152)   X2t bf16 [128][8192]
//   [37781504, +134217728) Hb  bf16 [8192][8192]  (dv_is-scaled)
// total ~172 MB
// ---------------------------------------------------------------------------
extern "C" void kernel_launch(void* const* d_in, const int* in_sizes, int n_in,
                              void* d_out, int out_size, void* d_ws, size_t ws_size,
                              hipStream_t stream) {
    const float* H = (const float*)d_in[0];
    const float* F = (const float*)d_in[1];
    float* out = (float*)d_out;
    char* ws = (char*)d_ws;

    float* part          = (float*)(ws);
    float* colpart       = (float*)(ws);
    float* de_inv        = (float*)(ws + 33554432);
    unsigned short* Fbt  = (unsigned short*)(ws + 33587200);
    unsigned short* X2t  = (unsigned short*)(ws + 35684352);
    unsigned short* Hb   = (unsigned short*)(ws + 37781504);

    deg_convert <<<512, 256, 0, stream>>>(H, Hb, colpart);
    finalize_deg<<<32, 256, 0, stream>>>(colpart, de_inv);
    make_fbt    <<<1024, 256, 0, stream>>>(F, Fbt);
    gemm_sk<1>  <<<dim3(64, 8), 256, 0, stream>>>(Hb, Fbt, part);
    reduce1     <<<1024, 256, 0, stream>>>(part, de_inv, X2t);
    gemm_sk<0>  <<<dim3(64, 8), 256, 0, stream>>>(Hb, X2t, part);
    reduce2     <<<4096, 256, 0, stream>>>(part, out);
}

// Round 3
// 177.587 us; speedup vs baseline: 1.1771x; 1.0857x over previous
//
#include <hip/hip_runtime.h>
#include <hip/hip_bf16.h>

#define EPSF 1e-10f

typedef short bf16x8 __attribute__((ext_vector_type(8)));
typedef float f32x4  __attribute__((ext_vector_type(4)));

__device__ __forceinline__ unsigned short f2bf(float f) {
    unsigned int u = __builtin_bit_cast(unsigned int, f);
    u += 0x7fffu + ((u >> 16) & 1u);   // round-to-nearest-even
    return (unsigned short)(u >> 16);
}

__device__ __forceinline__ void gload16(const void* g, void* l) {
    __builtin_amdgcn_global_load_lds(
        (const __attribute__((address_space(1))) void*)g,
        (__attribute__((address_space(3))) void*)l, 16, 0, 0);
}

// ---------------------------------------------------------------------------
// Pass 1: fold rsqrt(rowsum+eps) into bf16 copy of H; per-block col partials.
// 1024 blocks x 8 rows. Software-pipelined: next row's loads issued before the
// cross-wave reduce; raw s_barrier (no vmcnt drain) keeps them in flight.
// ---------------------------------------------------------------------------
__global__ __launch_bounds__(256) void deg_convert(const float* __restrict__ H,
                                                   unsigned short* __restrict__ Hb,
                                                   float* __restrict__ colpart) {
    const int t    = threadIdx.x;
    const int b    = blockIdx.x;          // 1024
    const int r0   = b * 8;
    const int lane = t & 63;
    const int wid  = t >> 6;
    __shared__ float wsum[2][4];

    float ca[32];
#pragma unroll
    for (int i = 0; i < 32; ++i) ca[i] = 0.f;

    float4 cur[8], nxt[8];
    {
        const float4* row = (const float4*)(H + (size_t)r0 * 8192);
#pragma unroll
        for (int j = 0; j < 8; ++j) cur[j] = row[j * 256 + t];
    }

    for (int r = 0; r < 8; ++r) {
        if (r < 7) {
            const float4* row = (const float4*)(H + (size_t)(r0 + r + 1) * 8192);
#pragma unroll
            for (int j = 0; j < 8; ++j) nxt[j] = row[j * 256 + t];
        }
        float rs = 0.f;
#pragma unroll
        for (int j = 0; j < 8; ++j) {
            ca[j * 4 + 0] += cur[j].x; ca[j * 4 + 1] += cur[j].y;
            ca[j * 4 + 2] += cur[j].z; ca[j * 4 + 3] += cur[j].w;
            rs += (cur[j].x + cur[j].y) + (cur[j].z + cur[j].w);
        }
#pragma unroll
        for (int off = 32; off; off >>= 1) rs += __shfl_down(rs, off, 64);
        if (lane == 0) wsum[r & 1][wid] = rs;
        asm volatile("s_waitcnt lgkmcnt(0)" ::: "memory");
        __builtin_amdgcn_s_barrier();            // raw: vmcnt (nxt loads) stays live
        asm volatile("" ::: "memory");
        const float s = rsqrtf(((wsum[r & 1][0] + wsum[r & 1][1]) +
                                (wsum[r & 1][2] + wsum[r & 1][3])) + EPSF);
        unsigned short* hrow = Hb + (size_t)(r0 + r) * 8192;
#pragma unroll
        for (int j = 0; j < 8; ++j) {
            ushort4 o;
            o.x = f2bf(cur[j].x * s); o.y = f2bf(cur[j].y * s);
            o.z = f2bf(cur[j].z * s); o.w = f2bf(cur[j].w * s);
            *(ushort4*)&hrow[j * 1024 + t * 4] = o;
        }
#pragma unroll
        for (int j = 0; j < 8; ++j) cur[j] = nxt[j];
    }

    float* cp = colpart + (size_t)b * 8192;
#pragma unroll
    for (int j = 0; j < 8; ++j) {
        float4 v;
        v.x = ca[j * 4 + 0]; v.y = ca[j * 4 + 1];
        v.z = ca[j * 4 + 2]; v.w = ca[j * 4 + 3];
        ((float4*)cp)[j * 256 + t] = v;
    }
}

// ---------------------------------------------------------------------------
// Fused: blocks [0,256) reduce colpart -> de_inv; blocks [256,1280) Fbt=bf16(F^T).
// ---------------------------------------------------------------------------
__global__ __launch_bounds__(256) void fin_fbt(const float* __restrict__ colpart,
                                               const float* __restrict__ F,
                                               float* __restrict__ de_inv,
                                               unsigned short* __restrict__ Fbt) {
    const int b = blockIdx.x;
    if (b < 256) {
        __shared__ float red[8][32];
        const int cl = threadIdx.x & 31;
        const int rg = threadIdx.x >> 5;
        const int col = b * 32 + cl;
        float s = 0.f;
#pragma unroll 4
        for (int rr = 0; rr < 128; ++rr)
            s += colpart[(size_t)(rg * 128 + rr) * 8192 + col];
        red[rg][cl] = s;
        __syncthreads();
        if (rg == 0) {
            float tot = 0.f;
#pragma unroll
            for (int g = 0; g < 8; ++g) tot += red[g][cl];
            de_inv[col] = 1.f / (tot + EPSF);
        }
    } else {
        const int idx = (b - 256) * 256 + threadIdx.x;   // 262144
        const int d   = idx & 127;
        const int n0  = (idx >> 7) * 4;
        ushort4 o;
        o.x = f2bf(F[(size_t)(n0 + 0) * 128 + d]);
        o.y = f2bf(F[(size_t)(n0 + 1) * 128 + d]);
        o.z = f2bf(F[(size_t)(n0 + 2) * 128 + d]);
        o.w = f2bf(F[(size_t)(n0 + 3) * 128 + d]);
        *(ushort4*)&Fbt[(size_t)d * 8192 + n0] = o;
    }
}

// ---------------------------------------------------------------------------
// Split-K GEMM on bf16 Hb.  C[8192][128] = A @ B, K = 8192 split 8 ways.
//   TRANS=1 (GEMM1): A[e][k] = Hb[k][e] (scalar col access, padded LDS)
//   TRANS=0 (GEMM2): A[n][k] = Hb[n][k] (global_load_lds, swizzled)
//   B stage always global_load_lds + swizzle.  Bt is [128][8192] bf16.
// Swizzle: LDS [128 rows][8 chunks x 16B]; slot chunk s of row r holds global
// chunk s^(r&7); frag read at kchunk uses slot kchunk^(r&7). 2 lanes/bank.
// ---------------------------------------------------------------------------
template <int TRANS>
__global__ __launch_bounds__(256) void gemm_sk(const unsigned short* __restrict__ Hb,
                                               const unsigned short* __restrict__ Bt,
                                               float* __restrict__ part) {
    constexpr int AROW = TRANS ? 72 : 64;
    __shared__ alignas(16) unsigned short As[128 * AROW];
    __shared__ alignas(16) unsigned short Bs[128 * 64];

    const int t    = threadIdx.x;
    const int lane = t & 63;
    const int wid  = t >> 6;
    const int wr   = (wid >> 1) * 64;
    const int wc   = (wid & 1) * 64;
    const int mb   = blockIdx.x;                 // 64
    const int sk   = blockIdx.y;                 // 8
    const size_t mbase = (size_t)mb * 128;
    const int kbase = sk * 1024;

    const int rloc8 = lane >> 3;                 // 0..7
    const int schnk = (lane & 7) ^ rloc8;        // pre-swizzled source chunk

    f32x4 acc[4][4];
#pragma unroll
    for (int m = 0; m < 4; ++m)
#pragma unroll
        for (int n = 0; n < 4; ++n)
#pragma unroll
            for (int i = 0; i < 4; ++i) acc[m][n][i] = 0.f;

    for (int kt = 0; kt < 1024; kt += 64) {
        const int k0 = kbase + kt;

        // ---- stage B tile via global_load_lds (4 instrs/wave) ----
#pragma unroll
        for (int q = 0; q < 4; ++q) {
            const int i   = wid * 4 + q;               // 0..15
            const int row = i * 8 + rloc8;             // 0..127
            gload16(Bt + (size_t)row * 8192 + k0 + schnk * 8,
                    (char*)Bs + i * 1024);
        }

        // ---- stage A tile ----
        if (TRANS == 0) {
#pragma unroll
            for (int q = 0; q < 4; ++q) {
                const int i   = wid * 4 + q;
                const int row = i * 8 + rloc8;
                gload16(Hb + (mbase + row) * 8192 + k0 + schnk * 8,
                        (char*)As + i * 1024);
            }
        } else {
            const int c = t & 127, kq = t >> 7;
            const unsigned short* base = Hb + mbase + c;
#pragma unroll
            for (int j = 0; j < 8; ++j) {
                const int kk0 = (j * 2 + kq) * 4;
                ushort4 o;
                o.x = base[(size_t)(k0 + kk0 + 0) * 8192];
                o.y = base[(size_t)(k0 + kk0 + 1) * 8192];
                o.z = base[(size_t)(k0 + kk0 + 2) * 8192];
                o.w = base[(size_t)(k0 + kk0 + 3) * 8192];
                *(ushort4*)&As[c * 72 + kk0] = o;
            }
        }
        __syncthreads();

        // ---- compute: 2 K-substeps of 16 MFMAs ----
        const char* asb = (const char*)As;
        const char* bsb = (const char*)Bs;
#pragma unroll
        for (int ks = 0; ks < 2; ++ks) {
            const int kch = ks * 4 + (lane >> 4);
            bf16x8 a[4], b[4];
#pragma unroll
            for (int m = 0; m < 4; ++m) {
                const int row = wr + m * 16 + (lane & 15);
                if (TRANS)
                    a[m] = *(const bf16x8*)&As[row * 72 + ks * 32 + (lane >> 4) * 8];
                else
                    a[m] = *(const bf16x8*)(asb + row * 128 + ((kch ^ (row & 7)) << 4));
            }
#pragma unroll
            for (int n = 0; n < 4; ++n) {
                const int row = wc + n * 16 + (lane & 15);
                b[n] = *(const bf16x8*)(bsb + row * 128 + ((kch ^ (row & 7)) << 4));
            }
#pragma unroll
            for (int m = 0; m < 4; ++m)
#pragma unroll
                for (int n = 0; n < 4; ++n)
                    acc[m][n] = __builtin_amdgcn_mfma_f32_16x16x32_bf16(a[m], b[n], acc[m][n], 0, 0, 0);
        }
        __syncthreads();
    }

    float* po = part + ((size_t)sk * 8192 + mbase) * 128;
#pragma unroll
    for (int m = 0; m < 4; ++m)
#pragma unroll
        for (int n = 0; n < 4; ++n)
#pragma unroll
            for (int r = 0; r < 4; ++r) {
                const int row = wr + m * 16 + (lane >> 4) * 4 + r;
                const int col = wc + n * 16 + (lane & 15);
                po[(size_t)row * 128 + col] = acc[m][n][r];
            }
}

// ---------------------------------------------------------------------------
// Reduce 8 split-K partials of GEMM1, scale by de_inv, write X2t[d][e] bf16.
// ---------------------------------------------------------------------------
__global__ __launch_bounds__(256) void reduce1(const float* __restrict__ part,
                                               const float* __restrict__ de_inv,
                                               unsigned short* __restrict__ X2t) {
    const int idx = blockIdx.x * 256 + threadIdx.x;   // 262144
    const int d   = idx & 127;
    const int e0  = (idx >> 7) * 4;
    ushort4 o;
#pragma unroll
    for (int i = 0; i < 4; ++i) {
        const size_t base = (size_t)(e0 + i) * 128 + d;
        float s = 0.f;
#pragma unroll
        for (int sk = 0; sk < 8; ++sk) s += part[base + (size_t)sk * 1048576];
        ((unsigned short*)&o)[i] = f2bf(s * de_inv[e0 + i]);
    }
    *(ushort4*)&X2t[(size_t)d * 8192 + e0] = o;
}

// ---------------------------------------------------------------------------
// Reduce 8 split-K partials of GEMM2 -> fp32 output (dv_is already folded).
// ---------------------------------------------------------------------------
__global__ __launch_bounds__(256) void reduce2(const float* __restrict__ part,
                                               float* __restrict__ out) {
    const int idx = blockIdx.x * 256 + threadIdx.x;   // 262144, float4 each
    const f32x4* p4 = (const f32x4*)part;
    f32x4 s = p4[idx];
#pragma unroll
    for (int sk = 1; sk < 8; ++sk) s += p4[idx + sk * 262144];
    ((f32x4*)out)[idx] = s;
}

// ---------------------------------------------------------------------------
// Workspace layout (bytes):
//   [0,        33554432)   colpart fp32 [1024][8192]  (dead after fin_fbt)
//                          aliased by split-K partials fp32 [8][8192][128]
//   [33554432, +32768)     de_inv
//   [33587200, +2097152)   Fbt bf16 [128][8192]
//   [35684352, +2097152)   X2t bf16 [128][8192]
//   [37781504, +134217728) Hb  bf16 [8192][8192]  (dv_is-scaled)
// total ~164 MB
// ---------------------------------------------------------------------------
extern "C" void kernel_launch(void* const* d_in, const int* in_sizes, int n_in,
                              void* d_out, int out_size, void* d_ws, size_t ws_size,
                              hipStream_t stream) {
    const float* H = (const float*)d_in[0];
    const float* F = (const float*)d_in[1];
    float* out = (float*)d_out;
    char* ws = (char*)d_ws;

    float* part          = (float*)(ws);
    float* colpart       = (float*)(ws);
    float* de_inv        = (float*)(ws + 33554432);
    unsigned short* Fbt  = (unsigned short*)(ws + 33587200);
    unsigned short* X2t  = (unsigned short*)(ws + 35684352);
    unsigned short* Hb   = (unsigned short*)(ws + 37781504);

    deg_convert <<<1024, 256, 0, stream>>>(H, Hb, colpart);
    fin_fbt     <<<1280, 256, 0, stream>>>(colpart, F, de_inv, Fbt);
    gemm_sk<1>  <<<dim3(64, 8), 256, 0, stream>>>(Hb, Fbt, part);
    reduce1     <<<1024, 256, 0, stream>>>(part, de_inv, X2t);
    gemm_sk<0>  <<<dim3(64, 8), 256, 0, stream>>>(Hb, X2t, part);
    reduce2     <<<1024, 256, 0, stream>>>(part, out);
}

// Round 4
// 172.921 us; speedup vs baseline: 1.2089x; 1.0270x over previous
//
#include <hip/hip_runtime.h>
#include <hip/hip_bf16.h>

#define EPSF 1e-10f

typedef short bf16x8 __attribute__((ext_vector_type(8)));
typedef float f32x4  __attribute__((ext_vector_type(4)));

__device__ __forceinline__ unsigned short f2bf(float f) {
    unsigned int u = __builtin_bit_cast(unsigned int, f);
    u += 0x7fffu + ((u >> 16) & 1u);   // round-to-nearest-even
    return (unsigned short)(u >> 16);
}

__device__ __forceinline__ void gload16(const void* g, void* l) {
    __builtin_amdgcn_global_load_lds(
        (const __attribute__((address_space(1))) void*)g,
        (__attribute__((address_space(3))) void*)l, 16, 0, 0);
}

// ---------------------------------------------------------------------------
// Pass 1: fold rsqrt(rowsum+eps) into bf16 copy of H; per-block col partials.
// 512 blocks x 16 rows, software-pipelined loads across a raw s_barrier.
// ---------------------------------------------------------------------------
__global__ __launch_bounds__(256) void deg_convert(const float* __restrict__ H,
                                                   unsigned short* __restrict__ Hb,
                                                   float* __restrict__ colpart) {
    const int t    = threadIdx.x;
    const int b    = blockIdx.x;          // 512
    const int r0   = b * 16;
    const int lane = t & 63;
    const int wid  = t >> 6;
    __shared__ float wsum[2][4];

    float ca[32];
#pragma unroll
    for (int i = 0; i < 32; ++i) ca[i] = 0.f;

    float4 cur[8], nxt[8];
    {
        const float4* row = (const float4*)(H + (size_t)r0 * 8192);
#pragma unroll
        for (int j = 0; j < 8; ++j) cur[j] = row[j * 256 + t];
    }

    for (int r = 0; r < 16; ++r) {
        if (r < 15) {
            const float4* row = (const float4*)(H + (size_t)(r0 + r + 1) * 8192);
#pragma unroll
            for (int j = 0; j < 8; ++j) nxt[j] = row[j * 256 + t];
        }
        float rs = 0.f;
#pragma unroll
        for (int j = 0; j < 8; ++j) {
            ca[j * 4 + 0] += cur[j].x; ca[j * 4 + 1] += cur[j].y;
            ca[j * 4 + 2] += cur[j].z; ca[j * 4 + 3] += cur[j].w;
            rs += (cur[j].x + cur[j].y) + (cur[j].z + cur[j].w);
        }
#pragma unroll
        for (int off = 32; off; off >>= 1) rs += __shfl_down(rs, off, 64);
        if (lane == 0) wsum[r & 1][wid] = rs;
        asm volatile("s_waitcnt lgkmcnt(0)" ::: "memory");
        __builtin_amdgcn_s_barrier();            // raw: nxt loads stay in flight
        asm volatile("" ::: "memory");
        const float s = rsqrtf(((wsum[r & 1][0] + wsum[r & 1][1]) +
                                (wsum[r & 1][2] + wsum[r & 1][3])) + EPSF);
        unsigned short* hrow = Hb + (size_t)(r0 + r) * 8192;
#pragma unroll
        for (int j = 0; j < 8; ++j) {
            ushort4 o;
            o.x = f2bf(cur[j].x * s); o.y = f2bf(cur[j].y * s);
            o.z = f2bf(cur[j].z * s); o.w = f2bf(cur[j].w * s);
            *(ushort4*)&hrow[j * 1024 + t * 4] = o;
        }
#pragma unroll
        for (int j = 0; j < 8; ++j) cur[j] = nxt[j];
    }

    float* cp = colpart + (size_t)b * 8192;
#pragma unroll
    for (int j = 0; j < 8; ++j) {
        float4 v;
        v.x = ca[j * 4 + 0]; v.y = ca[j * 4 + 1];
        v.z = ca[j * 4 + 2]; v.w = ca[j * 4 + 3];
        ((float4*)cp)[j * 256 + t] = v;
    }
}

// ---------------------------------------------------------------------------
// Fused: blocks [0,256) reduce colpart -> de_inv; blocks [256,1280) Fbt=bf16(F^T).
// ---------------------------------------------------------------------------
__global__ __launch_bounds__(256) void fin_fbt(const float* __restrict__ colpart,
                                               const float* __restrict__ F,
                                               float* __restrict__ de_inv,
                                               unsigned short* __restrict__ Fbt) {
    const int b = blockIdx.x;
    if (b < 256) {
        __shared__ float red[8][32];
        const int cl = threadIdx.x & 31;
        const int rg = threadIdx.x >> 5;
        const int col = b * 32 + cl;
        float s = 0.f;
#pragma unroll 4
        for (int rr = 0; rr < 64; ++rr)
            s += colpart[(size_t)(rg * 64 + rr) * 8192 + col];
        red[rg][cl] = s;
        __syncthreads();
        if (rg == 0) {
            float tot = 0.f;
#pragma unroll
            for (int g = 0; g < 8; ++g) tot += red[g][cl];
            de_inv[col] = 1.f / (tot + EPSF);
        }
    } else {
        const int idx = (b - 256) * 256 + threadIdx.x;   // 262144
        const int d   = idx & 127;
        const int n0  = (idx >> 7) * 4;
        ushort4 o;
        o.x = f2bf(F[(size_t)(n0 + 0) * 128 + d]);
        o.y = f2bf(F[(size_t)(n0 + 1) * 128 + d]);
        o.z = f2bf(F[(size_t)(n0 + 2) * 128 + d]);
        o.w = f2bf(F[(size_t)(n0 + 3) * 128 + d]);
        *(ushort4*)&Fbt[(size_t)d * 8192 + n0] = o;
    }
}

// ---------------------------------------------------------------------------
// Split-K GEMM on bf16 Hb, 2-phase double-buffered.
// C[8192][128] = A @ B, K = 8192 split 8 ways.
//   TRANS=1 (GEMM1): A[e][k] = Hb[k][e]  (reg-prefetch scalar cols -> ds_write)
//   TRANS=0 (GEMM2): A[n][k] = Hb[n][k]  (global_load_lds)
//   B always global_load_lds.  Bt is [128][8192] bf16 (k-contiguous).
// LDS layout (both operands): [128 rows][8 chunks x 16B]; slot chunk s of row
// r holds k-chunk s^(r&7); frag read at kchunk kc uses slot kc^(r&7).
// ---------------------------------------------------------------------------
template <int TRANS>
__global__ __launch_bounds__(256) void gemm_sk(const unsigned short* __restrict__ Hb,
                                               const unsigned short* __restrict__ Bt,
                                               float* __restrict__ part) {
    __shared__ alignas(16) unsigned short As[2][8192];
    __shared__ alignas(16) unsigned short Bs[2][8192];

    const int t    = threadIdx.x;
    const int lane = t & 63;
    const int wid  = t >> 6;
    const int wr   = (wid >> 1) * 64;
    const int wc   = (wid & 1) * 64;
    const size_t mbase = (size_t)blockIdx.x * 128;
    const int kbase = blockIdx.y * 1024;

    const int rloc8 = lane >> 3;                 // 0..7
    const int schnk = (lane & 7) ^ rloc8;        // pre-swizzled source chunk
    const int c  = t & 127;                      // TRANS=1 A column
    const int kq = t >> 7;

    f32x4 acc[4][4];
#pragma unroll
    for (int m = 0; m < 4; ++m)
#pragma unroll
        for (int n = 0; n < 4; ++n)
#pragma unroll
            for (int i = 0; i < 4; ++i) acc[m][n][i] = 0.f;

    auto stageB = [&](int p, int k0) {
#pragma unroll
        for (int q = 0; q < 4; ++q) {
            const int i = wid * 4 + q;
            gload16(Bt + (size_t)(i * 8 + rloc8) * 8192 + k0 + schnk * 8,
                    (char*)Bs[p] + i * 1024);
        }
    };
    auto stageA0 = [&](int p, int k0) {
#pragma unroll
        for (int q = 0; q < 4; ++q) {
            const int i = wid * 4 + q;
            gload16(Hb + (mbase + i * 8 + rloc8) * 8192 + k0 + schnk * 8,
                    (char*)As[p] + i * 1024);
        }
    };
    auto loadA1 = [&](int k0, ushort4* r) {
        const unsigned short* base = Hb + mbase + c;
#pragma unroll
        for (int j = 0; j < 8; ++j) {
            const int kk = k0 + (j * 2 + kq) * 4;
            r[j].x = base[(size_t)(kk + 0) * 8192];
            r[j].y = base[(size_t)(kk + 1) * 8192];
            r[j].z = base[(size_t)(kk + 2) * 8192];
            r[j].w = base[(size_t)(kk + 3) * 8192];
        }
    };
    auto writeA1 = [&](int p, const ushort4* r) {
#pragma unroll
        for (int j = 0; j < 8; ++j)
            *(ushort4*)((char*)As[p] + c * 128 + (((j ^ (c & 7)) << 4) + kq * 8)) = r[j];
    };
    auto compute = [&](int p) {
        const char* asb = (const char*)As[p];
        const char* bsb = (const char*)Bs[p];
#pragma unroll
        for (int ks = 0; ks < 2; ++ks) {
            const int kch = ks * 4 + (lane >> 4);
            bf16x8 a[4], b[4];
#pragma unroll
            for (int m = 0; m < 4; ++m) {
                const int row = wr + m * 16 + (lane & 15);
                a[m] = *(const bf16x8*)(asb + row * 128 + ((kch ^ (row & 7)) << 4));
            }
#pragma unroll
            for (int n = 0; n < 4; ++n) {
                const int row = wc + n * 16 + (lane & 15);
                b[n] = *(const bf16x8*)(bsb + row * 128 + ((kch ^ (row & 7)) << 4));
            }
#pragma unroll
            for (int m = 0; m < 4; ++m)
#pragma unroll
                for (int n = 0; n < 4; ++n)
                    acc[m][n] = __builtin_amdgcn_mfma_f32_16x16x32_bf16(a[m], b[n], acc[m][n], 0, 0, 0);
        }
    };

    if (TRANS == 0) {
        stageB(0, kbase);
        stageA0(0, kbase);
        for (int tt = 0; tt < 16; ++tt) {
            const int p = tt & 1;
            if (tt < 15) {
                stageB(p ^ 1, kbase + (tt + 1) * 64);
                stageA0(p ^ 1, kbase + (tt + 1) * 64);
                asm volatile("s_waitcnt vmcnt(8)" ::: "memory");
            } else {
                asm volatile("s_waitcnt vmcnt(0)" ::: "memory");
            }
            __builtin_amdgcn_s_barrier();
            asm volatile("" ::: "memory");
            compute(p);
            asm volatile("s_waitcnt lgkmcnt(0)" ::: "memory");
            __builtin_amdgcn_s_barrier();
            asm volatile("" ::: "memory");
        }
    } else {
        ushort4 rA[8], rB2[8];
        stageB(0, kbase);
        loadA1(kbase, rA);
        for (int tt = 0; tt < 16; tt += 2) {
            // ---- tile tt (buffers 0) ----
            if (tt + 1 < 16) {
                stageB(1, kbase + (tt + 1) * 64);
                loadA1(kbase + (tt + 1) * 64, rB2);
            }
            writeA1(0, rA);        // compiler waits rA's loads -> B(tt) also landed
            asm volatile("s_waitcnt vmcnt(36) lgkmcnt(0)" ::: "memory");
            __builtin_amdgcn_s_barrier();
            asm volatile("" ::: "memory");
            compute(0);
            asm volatile("s_waitcnt lgkmcnt(0)" ::: "memory");
            __builtin_amdgcn_s_barrier();
            asm volatile("" ::: "memory");
            // ---- tile tt+1 (buffers 1) ----
            if (tt + 2 < 16) {
                stageB(0, kbase + (tt + 2) * 64);
                loadA1(kbase + (tt + 2) * 64, rA);
                writeA1(1, rB2);
                asm volatile("s_waitcnt vmcnt(36) lgkmcnt(0)" ::: "memory");
            } else {
                writeA1(1, rB2);
                asm volatile("s_waitcnt vmcnt(0) lgkmcnt(0)" ::: "memory");
            }
            __builtin_amdgcn_s_barrier();
            asm volatile("" ::: "memory");
            compute(1);
            asm volatile("s_waitcnt lgkmcnt(0)" ::: "memory");
            __builtin_amdgcn_s_barrier();
            asm volatile("" ::: "memory");
        }
    }

    float* po = part + ((size_t)blockIdx.y * 8192 + mbase) * 128;
#pragma unroll
    for (int m = 0; m < 4; ++m)
#pragma unroll
        for (int n = 0; n < 4; ++n)
#pragma unroll
            for (int r = 0; r < 4; ++r) {
                const int row = wr + m * 16 + (lane >> 4) * 4 + r;
                const int col = wc + n * 16 + (lane & 15);
                po[(size_t)row * 128 + col] = acc[m][n][r];
            }
}

// ---------------------------------------------------------------------------
// Reduce 8 split-K partials of GEMM1, scale by de_inv, write X2t[d][e] bf16.
// ---------------------------------------------------------------------------
__global__ __launch_bounds__(256) void reduce1(const float* __restrict__ part,
                                               const float* __restrict__ de_inv,
                                               unsigned short* __restrict__ X2t) {
    const int idx = blockIdx.x * 256 + threadIdx.x;   // 262144
    const int d   = idx & 127;
    const int e0  = (idx >> 7) * 4;
    ushort4 o;
#pragma unroll
    for (int i = 0; i < 4; ++i) {
        const size_t base = (size_t)(e0 + i) * 128 + d;
        float s = 0.f;
#pragma unroll
        for (int sk = 0; sk < 8; ++sk) s += part[base + (size_t)sk * 1048576];
        ((unsigned short*)&o)[i] = f2bf(s * de_inv[e0 + i]);
    }
    *(ushort4*)&X2t[(size_t)d * 8192 + e0] = o;
}

// ---------------------------------------------------------------------------
// Reduce 8 split-K partials of GEMM2 -> fp32 output (dv_is already folded).
// ---------------------------------------------------------------------------
__global__ __launch_bounds__(256) void reduce2(const float* __restrict__ part,
                                               float* __restrict__ out) {
    const int idx = blockIdx.x * 256 + threadIdx.x;   // 262144, float4 each
    const f32x4* p4 = (const f32x4*)part;
    f32x4 s = p4[idx];
#pragma unroll
    for (int sk = 1; sk < 8; ++sk) s += p4[idx + sk * 262144];
    ((f32x4*)out)[idx] = s;
}

// ---------------------------------------------------------------------------
// Workspace layout (bytes):
//   [0,        33554432)   split-K partials fp32 [8][8192][128]  (32 MB)
//                          (first 16 MB aliased as colpart [512][8192], dead
//                           after fin_fbt)
//   [33554432, +32768)     de_inv
//   [33587200, +2097152)   Fbt bf16 [128][8192]
//   [35684352, +2097152)   X2t bf16 [128][8192]
//   [37781504, +134217728) Hb  bf16 [8192][8192]  (dv_is-scaled)
// ---------------------------------------------------------------------------
extern "C" void kernel_launch(void* const* d_in, const int* in_sizes, int n_in,
                              void* d_out, int out_size, void* d_ws, size_t ws_size,
                              hipStream_t stream) {
    const float* H = (const float*)d_in[0];
    const float* F = (const float*)d_in[1];
    float* out = (float*)d_out;
    char* ws = (char*)d_ws;

    float* part          = (float*)(ws);
    float* colpart       = (float*)(ws);
    float* de_inv        = (float*)(ws + 33554432);
    unsigned short* Fbt  = (unsigned short*)(ws + 33587200);
    unsigned short* X2t  = (unsigned short*)(ws + 35684352);
    unsigned short* Hb   = (unsigned short*)(ws + 37781504);

    deg_convert <<<512, 256, 0, stream>>>(H, Hb, colpart);
    fin_fbt     <<<1280, 256, 0, stream>>>(colpart, F, de_inv, Fbt);
    gemm_sk<1>  <<<dim3(64, 8), 256, 0, stream>>>(Hb, Fbt, part);
    reduce1     <<<1024, 256, 0, stream>>>(part, de_inv, X2t);
    gemm_sk<0>  <<<dim3(64, 8), 256, 0, stream>>>(Hb, X2t, part);
    reduce2     <<<1024, 256, 0, stream>>>(part, out);
}